// Round 9
// baseline (345.484 us; speedup 1.0000x reference)
//
#include <hip/hip_runtime.h>
#include <math.h>

#define NBOX 1024
#define ROI_N 7
#define CH 32
#define FEAT (ROI_N*ROI_N*CH)   // 1568
#define K1PAD 1792              // FEAT padded to multiple of 256 (4 chunks x 64)
#define HD 2048
#define NMS_THR_F 0.01f
#define NMS_OUT 100
#define MTRI_WORDS 8704

typedef _Float16 f16;
typedef f16 f16x4 __attribute__((ext_vector_type(4)));
typedef f16 f16x8 __attribute__((ext_vector_type(8)));
typedef float f32x4 __attribute__((ext_vector_type(4)));

__device__ __forceinline__ void split_f16(float v, f16& h, f16& l) {
  h = (f16)v;
  l = (f16)((v - (float)h) * 4096.0f);
}

__device__ __forceinline__ void gload_lds16(const void* g, void* l) {
  __builtin_amdgcn_global_load_lds(
      (const __attribute__((address_space(1))) unsigned int*)g,
      (__attribute__((address_space(3))) unsigned int*)l, 16, 0, 0);
}

// ============ prep: roi_fuse + convt(W1/W2) + bias-init + head-weight transpose ============
#define B_ROI 1024
#define B_C1  (64*28)    // (HD/32) x (K1PAD/64)
#define B_C2  (64*32)    // (HD/32) x (HD/64)
#define B_INIT 2048      // NBOX*HD/4/256
#define B_HT  112        // 14*HD/256

__device__ void roi_part(int b, int tid,
    const float* __restrict__ img, const float* __restrict__ bev,
    const float* __restrict__ img_boxes, const float* __restrict__ bev_boxes,
    float mi, float mb, f16* __restrict__ xh, f16* __restrict__ xl)
{
  const float denom = mi + mb;
  if (tid >= 196) {
    const int g = tid - 196;
    if (g < 28) {        // zero-pad FEAT..K1PAD (224 f16 = 28 chunks of 8)
      f16x8 z = {};
      *(f16x8*)&xh[(size_t)b*K1PAD + FEAT + g*8] = z;
      *(f16x8*)&xl[(size_t)b*K1PAD + FEAT + g*8] = z;
    }
    return;
  }
  const int cell = tid >> 2, cg = (tid & 3) * 8;
  const int ti = cell / ROI_N, tj = cell - ti*ROI_N;
  const float tt_i = (ti == 6) ? 1.0f : ti * (1.0f/6.0f);
  const float tt_j = (tj == 6) ? 1.0f : tj * (1.0f/6.0f);

  float vi[8], vb[8];
  {
    const int H = 360, W = 1200;
    const float iy0 = img_boxes[b*4+0], ix0 = img_boxes[b*4+1];
    const float iy1 = img_boxes[b*4+2], ix1 = img_boxes[b*4+3];
    const float ys = (iy0 + (iy1 - iy0) * tt_i) * (float)(H-1);
    const float xs = (ix0 + (ix1 - ix0) * tt_j) * (float)(W-1);
    int y0 = (int)floorf(ys); y0 = y0 < 0 ? 0 : (y0 > H-1 ? H-1 : y0);
    int x0 = (int)floorf(xs); x0 = x0 < 0 ? 0 : (x0 > W-1 ? W-1 : x0);
    const int y1 = (y0+1 > H-1) ? H-1 : y0+1;
    const int x1 = (x0+1 > W-1) ? W-1 : x0+1;
    const float wy = ys - (float)y0, wx = xs - (float)x0;
    const float w00 = (1.0f-wy)*(1.0f-wx), w01 = (1.0f-wy)*wx;
    const float w10 = wy*(1.0f-wx),        w11 = wy*wx;
    const float* p00 = &img[(y0*W + x0)*CH + cg];
    const float* p01 = &img[(y0*W + x1)*CH + cg];
    const float* p10 = &img[(y1*W + x0)*CH + cg];
    const float* p11 = &img[(y1*W + x1)*CH + cg];
#pragma unroll
    for (int q = 0; q < 2; ++q) {
      const float4 f00 = *(const float4*)(p00 + q*4);
      const float4 f01 = *(const float4*)(p01 + q*4);
      const float4 f10 = *(const float4*)(p10 + q*4);
      const float4 f11 = *(const float4*)(p11 + q*4);
      vi[q*4+0] = f00.x*w00 + f01.x*w01 + f10.x*w10 + f11.x*w11;
      vi[q*4+1] = f00.y*w00 + f01.y*w01 + f10.y*w10 + f11.y*w11;
      vi[q*4+2] = f00.z*w00 + f01.z*w01 + f10.z*w10 + f11.z*w11;
      vi[q*4+3] = f00.w*w00 + f01.w*w01 + f10.w*w10 + f11.w*w11;
    }
  }
  {
    const int H = 700, W = 800;
    const float by0 = bev_boxes[b*4+0], bx0 = bev_boxes[b*4+1];
    const float by1 = bev_boxes[b*4+2], bx1 = bev_boxes[b*4+3];
    const float ys = (by0 + (by1 - by0) * tt_i) * (float)(H-1);
    const float xs = (bx0 + (bx1 - bx0) * tt_j) * (float)(W-1);
    int y0 = (int)floorf(ys); y0 = y0 < 0 ? 0 : (y0 > H-1 ? H-1 : y0);
    int x0 = (int)floorf(xs); x0 = x0 < 0 ? 0 : (x0 > W-1 ? W-1 : x0);
    const int y1 = (y0+1 > H-1) ? H-1 : y0+1;
    const int x1 = (x0+1 > W-1) ? W-1 : x0+1;
    const float wy = ys - (float)y0, wx = xs - (float)x0;
    const float w00 = (1.0f-wy)*(1.0f-wx), w01 = (1.0f-wy)*wx;
    const float w10 = wy*(1.0f-wx),        w11 = wy*wx;
    const float* p00 = &bev[(y0*W + x0)*CH + cg];
    const float* p01 = &bev[(y0*W + x1)*CH + cg];
    const float* p10 = &bev[(y1*W + x0)*CH + cg];
    const float* p11 = &bev[(y1*W + x1)*CH + cg];
#pragma unroll
    for (int q = 0; q < 2; ++q) {
      const float4 f00 = *(const float4*)(p00 + q*4);
      const float4 f01 = *(const float4*)(p01 + q*4);
      const float4 f10 = *(const float4*)(p10 + q*4);
      const float4 f11 = *(const float4*)(p11 + q*4);
      vb[q*4+0] = f00.x*w00 + f01.x*w01 + f10.x*w10 + f11.x*w11;
      vb[q*4+1] = f00.y*w00 + f01.y*w01 + f10.y*w10 + f11.y*w11;
      vb[q*4+2] = f00.z*w00 + f01.z*w01 + f10.z*w10 + f11.z*w11;
      vb[q*4+3] = f00.w*w00 + f01.w*w01 + f10.w*w10 + f11.w*w11;
    }
  }
  f16x8 h8, l8;
#pragma unroll
  for (int q = 0; q < 8; ++q) {
    f16 h, l;
    split_f16((mi*vi[q] + mb*vb[q]) / denom, h, l);
    h8[q] = h; l8[q] = l;
  }
  const size_t o = (size_t)b*K1PAD + cell*32 + cg;
  *(f16x8*)&xh[o] = h8;
  *(f16x8*)&xl[o] = l8;
}

__global__ __launch_bounds__(256) void prep_kernel(
    const float* __restrict__ img, const float* __restrict__ bev,
    const float* __restrict__ img_boxes, const float* __restrict__ bev_boxes,
    const float* __restrict__ img_mask, const float* __restrict__ bev_mask,
    f16* __restrict__ xh, f16* __restrict__ xl,
    const float* __restrict__ W1, f16* __restrict__ Wt1h, f16* __restrict__ Wt1l,
    const float* __restrict__ W2, f16* __restrict__ Wt2h, f16* __restrict__ Wt2l,
    const float* __restrict__ b1, const float* __restrict__ b2,
    float4* __restrict__ h1f, float4* __restrict__ h2f,
    const float* __restrict__ Wc, const float* __restrict__ Wo,
    const float* __restrict__ Wa, float* __restrict__ Wcat,
    unsigned long long* __restrict__ rowAny)
{
  __shared__ float t[64][33];
  const int g = blockIdx.x;
  const int tid = threadIdx.x;

  if (g < B_ROI) {
    roi_part(g, tid, img, bev, img_boxes, bev_boxes, img_mask[0], bev_mask[0], xh, xl);
    return;
  }
  if (g >= B_ROI + B_C1 + B_C2 + B_INIT) {   // head-weight transpose
    const int idx = (g - (B_ROI + B_C1 + B_C2 + B_INIT))*256 + tid;  // 0..14*HD-1
    const int j = idx >> 11, k = idx & (HD-1);
    float v;
    if (j < 2)       v = Wc[k*2 + j];
    else if (j < 12) v = Wo[k*10 + (j-2)];
    else             v = Wa[k*2 + (j-12)];
    Wcat[idx] = v;
    return;
  }
  const float* W; f16 *Wh, *Wl; int K, Kpad, cb;
  if (g < B_ROI + B_C1) { cb = g - B_ROI;        W = W1; Wh = Wt1h; Wl = Wt1l; K = FEAT; Kpad = K1PAD; }
  else if (g < B_ROI + B_C1 + B_C2) { cb = g - B_ROI - B_C1; W = W2; Wh = Wt2h; Wl = Wt2l; K = HD; Kpad = HD; }
  else {
    const int ib = g - B_ROI - B_C1 - B_C2;
    const int idx = ib*256 + tid;
    const int c4 = idx & (HD/4 - 1);
    h1f[idx] = *(const float4*)&b1[c4*4];
    h2f[idx] = *(const float4*)&b2[c4*4];
    if (idx < 16) rowAny[idx] = 0ull;
    return;
  }
  const int nt = cb & 63, kt = cb >> 6;
  const int n0 = nt * 32, k0 = kt * 64;
#pragma unroll
  for (int p = 0; p < 8; ++p) {
    const int idx = tid + p*256;
    const int kk = idx >> 5, nn = idx & 31;
    const int k = k0 + kk;
    t[kk][nn] = (k < K) ? W[(size_t)k*HD + n0 + nn] : 0.0f;
  }
  __syncthreads();
  const int nn = tid >> 3;
  const int kg = (tid & 7) * 8;
  f16x8 h8, l8;
#pragma unroll
  for (int q = 0; q < 8; ++q) {
    f16 h, l;
    split_f16(t[kg + q][nn], h, l);
    h8[q] = h; l8[q] = l;
  }
  *(f16x8*)&Wh[(size_t)(n0+nn)*Kpad + k0 + kg] = h8;
  *(f16x8*)&Wl[(size_t)(n0+nn)*Kpad + k0 + kg] = l8;
}

// ---------------- relu + f16 hi/lo split of h1 ----------------
__global__ __launch_bounds__(256) void split_relu_kernel(
    const float* __restrict__ in, f16* __restrict__ oh, f16* __restrict__ ol)
{
  const int idx = blockIdx.x*256 + threadIdx.x;
  const float4 v = *(const float4*)&in[idx*4];
  f16x4 h4, l4;
  { f16 h,l; split_f16(fmaxf(v.x,0.0f),h,l); h4[0]=h; l4[0]=l; }
  { f16 h,l; split_f16(fmaxf(v.y,0.0f),h,l); h4[1]=h; l4[1]=l; }
  { f16 h,l; split_f16(fmaxf(v.z,0.0f),h,l); h4[2]=h; l4[2]=l; }
  { f16 h,l; split_f16(fmaxf(v.w,0.0f),h,l); h4[3]=h; l4[3]=l; }
  *(f16x4*)&oh[idx*4] = h4;
  *(f16x4*)&ol[idx*4] = l4;
}

// ---------------- MFMA GEMM: split-K=4 atomics, BK=64 single-buffer (m97 shape) ----------------
// Cout (pre-init with bias) += (Ah+Al/4096) @ (Bh+Bl/4096)^T, dropping lo*lo.
// Block 256 thr = 4 waves (2x2), tile 128x128, BK=64.
// LDS [4 arrays][128 rows][8 slots of 16B]; slot' = slot ^ (row&7) (XOR bank swizzle).
// Stage: 16 global_load_lds dwordx4 per wave; source col offset per-lane constant.
__global__ __launch_bounds__(256, 2) void gemm_sk(
    const f16* __restrict__ Ah_g, const f16* __restrict__ Al_g,
    const f16* __restrict__ Bh_g, const f16* __restrict__ Bl_g,
    float* __restrict__ Cout, int M, int N, int K, int kchunk)
{
  __shared__ __align__(16) f16 lds4[4][128*64];   // 64 KB
  const int tid = threadIdx.x;

  const int g = blockIdx.x;
  const int xcd = g & 7, c = g >> 3;
  const int nb = xcd*2 + (c & 1);
  const int mb = (c >> 1) & 7;
  const int zb = c >> 4;
  const int m0 = mb * 128, n0 = nb * 128;
  const int kb = zb * kchunk, ke = kb + kchunk;

  const int wid = tid >> 6, lane = tid & 63;
  const int wr = wid >> 1, wc = wid & 1;
  const int frow = lane & 15, fkg = lane >> 4;

  // staging: wave -> one array; per-lane constant source column (inverse swizzle)
  const f16* sarr; int rbase;
  if (wid == 0)      { sarr = Ah_g; rbase = m0; }
  else if (wid == 1) { sarr = Al_g; rbase = m0; }
  else if (wid == 2) { sarr = Bh_g; rbase = n0; }
  else               { sarr = Bl_g; rbase = n0; }
  f16* lbase = &lds4[wid][0];
  const int rowL = lane >> 3;                 // 0..7
  const int colOff = ((lane & 7) ^ rowL) * 8; // f16 units, constant per lane
  const f16* sl = sarr + (size_t)(rbase + rowL)*K + colOff;

  f32x4 acc1[4][4], acc2[4][4];
#pragma unroll
  for (int i = 0; i < 4; ++i)
#pragma unroll
    for (int j = 0; j < 4; ++j)
#pragma unroll
      for (int r = 0; r < 4; ++r) { acc1[i][j][r] = 0.0f; acc2[i][j][r] = 0.0f; }

  for (int kk = kb; kk < ke; kk += 64) {
    __syncthreads();                      // previous compute's LDS reads done
#pragma unroll
    for (int q = 0; q < 16; ++q)
      gload_lds16(sl + (size_t)(q*8)*K + kk, lbase + q*512);
    __syncthreads();                      // drain: tile resident

#pragma unroll
    for (int kc = 0; kc < 2; ++kc) {
      const int qs = kc*4 + fkg;          // logical slot for this fragment
      f16x8 bh[4], bl[4];
#pragma unroll
      for (int j = 0; j < 4; ++j) {
        const int rr = wc*64 + j*16 + frow;
        const int so = rr*64 + ((qs ^ (rr & 7)) * 8);
        bh[j] = *(const f16x8*)&lds4[2][so];
        bl[j] = *(const f16x8*)&lds4[3][so];
      }
#pragma unroll
      for (int i = 0; i < 4; ++i) {
        const int rr = wr*64 + i*16 + frow;
        const int so = rr*64 + ((qs ^ (rr & 7)) * 8);
        const f16x8 ah = *(const f16x8*)&lds4[0][so];
        const f16x8 al = *(const f16x8*)&lds4[1][so];
#pragma unroll
        for (int j = 0; j < 4; ++j) {
          acc1[i][j] = __builtin_amdgcn_mfma_f32_16x16x32_f16(ah, bh[j], acc1[i][j], 0, 0, 0);
          acc2[i][j] = __builtin_amdgcn_mfma_f32_16x16x32_f16(ah, bl[j], acc2[i][j], 0, 0, 0);
          acc2[i][j] = __builtin_amdgcn_mfma_f32_16x16x32_f16(al, bh[j], acc2[i][j], 0, 0, 0);
        }
      }
    }
  }

  const float s = 1.0f / 4096.0f;
#pragma unroll
  for (int i = 0; i < 4; ++i)
#pragma unroll
    for (int j = 0; j < 4; ++j) {
      const int col = n0 + wc*64 + j*16 + frow;
#pragma unroll
      for (int r = 0; r < 4; ++r) {
        const int row = m0 + wr*64 + i*16 + fkg*4 + r;
        atomicAdd(&Cout[(size_t)row*N + col], acc1[i][j][r] + acc2[i][j][r] * s);
      }
    }
}

// ---------------- heads: vectorized via transposed Wcat[14][HD] ----------------
__global__ __launch_bounds__(256) void heads_kernel(
    const float* __restrict__ h2f, const float* __restrict__ Wcat,
    const float* __restrict__ bc, const float* __restrict__ bo,
    const float* __restrict__ ba, const float* __restrict__ bev_abs,
    float* __restrict__ obj_soft, float* __restrict__ boxes,
    float* __restrict__ orient, float* __restrict__ scores)
{
  const int r = blockIdx.x;
  const int tid = threadIdx.x;
  const int k0 = tid * 8;
  float4 hv0 = *(const float4*)&h2f[(size_t)r*HD + k0];
  float4 hv1 = *(const float4*)&h2f[(size_t)r*HD + k0 + 4];
  hv0.x = fmaxf(hv0.x, 0.0f); hv0.y = fmaxf(hv0.y, 0.0f);
  hv0.z = fmaxf(hv0.z, 0.0f); hv0.w = fmaxf(hv0.w, 0.0f);
  hv1.x = fmaxf(hv1.x, 0.0f); hv1.y = fmaxf(hv1.y, 0.0f);
  hv1.z = fmaxf(hv1.z, 0.0f); hv1.w = fmaxf(hv1.w, 0.0f);

  float acc[14];
#pragma unroll
  for (int j = 0; j < 14; ++j) {
    const float4 w0 = *(const float4*)&Wcat[j*HD + k0];
    const float4 w1 = *(const float4*)&Wcat[j*HD + k0 + 4];
    acc[j] = hv0.x*w0.x + hv0.y*w0.y + hv0.z*w0.z + hv0.w*w0.w
           + hv1.x*w1.x + hv1.y*w1.y + hv1.z*w1.z + hv1.w*w1.w;
  }
  __shared__ float red[14][256];
#pragma unroll
  for (int j = 0; j < 14; ++j) red[j][tid] = acc[j];
  __syncthreads();
  for (int s = 128; s > 0; s >>= 1) {
    if (tid < s) {
#pragma unroll
      for (int j = 0; j < 14; ++j) red[j][tid] += red[j][tid + s];
    }
    __syncthreads();
  }
  if (tid == 0) {
    const float obj0 = red[0][0] + bc[0];
    const float obj1 = red[1][0] + bc[1];
    const float off0 = red[2][0] + bo[0];
    const float off1 = red[3][0] + bo[1];
    const float off2 = red[4][0] + bo[2];
    const float off3 = red[5][0] + bo[3];
    const float a0 = red[12][0] + ba[0];
    const float a1 = red[13][0] + ba[1];

    const float m  = fmaxf(obj0, obj1);
    const float e0 = expf(obj0 - m), e1 = expf(obj1 - m);
    const float se = e0 + e1;
    obj_soft[r*2+0] = e0 / se;
    obj_soft[r*2+1] = e1 / se;
    orient[r] = atan2f(a1, a0);

    const float pb0 = bev_abs[r*4+0] + 0.1f*off0;
    const float pb1 = bev_abs[r*4+1] + 0.1f*off1;
    const float pb2 = bev_abs[r*4+2] + 0.1f*off2;
    const float pb3 = bev_abs[r*4+3] + 0.1f*off3;
    boxes[r*4+0] = fminf(pb0, pb2);
    boxes[r*4+1] = fminf(pb1, pb3);
    boxes[r*4+2] = fmaxf(pb0, pb2);
    boxes[r*4+3] = fmaxf(pb1, pb3);
    scores[r] = obj1;
  }
}

// ---------------- NMS stage 1 (scores staged in LDS) ----------------
__global__ __launch_bounds__(128) void sort_kernel(
    const float* __restrict__ scores, const float* __restrict__ boxes,
    int* __restrict__ order, float4* __restrict__ sboxes, float* __restrict__ sarea)
{
  __shared__ float ss[NBOX];
  const int tid = threadIdx.x;
  for (int t = tid; t < NBOX; t += 128) ss[t] = scores[t];
  __syncthreads();
  const int i = blockIdx.x * 128 + tid;
  const float my = ss[i];
  int pos = 0;
  for (int j = 0; j < NBOX; ++j) {
    const float sj = ss[j];
    pos += (sj > my) || (sj == my && j < i);
  }
  const float b0 = boxes[i*4+0], b1 = boxes[i*4+1];
  const float b2 = boxes[i*4+2], b3 = boxes[i*4+3];
  order[pos]  = i;
  sboxes[pos] = make_float4(b0, b1, b2, b3);
  sarea[pos]  = fmaxf(b2 - b0, 0.0f) * fmaxf(b3 - b1, 0.0f);
}

// ---------------- NMS stage 2: triangular mask + rowAny bitmap ----------------
__device__ __forceinline__ int tri_base(int i) {
  const int b = i >> 6;
  return 64*(16*b - (b*(b-1))/2) + (i & 63)*(16 - b);
}

__global__ __launch_bounds__(256) void maskbuild_kernel(
    const float4* __restrict__ sboxes, const float* __restrict__ sarea,
    unsigned long long* __restrict__ Mtri, unsigned long long* __restrict__ rowAny)
{
  __shared__ float4 sb[NBOX];
  __shared__ float  sa[NBOX];
  const int tid = threadIdx.x;
  for (int t = tid; t < NBOX; t += 256) { sb[t] = sboxes[t]; sa[t] = sarea[t]; }
  __syncthreads();
  const int wv = tid >> 6, lane = tid & 63;
  for (int r = 0; r < 4; ++r) {
    const int i = blockIdx.x * 16 + wv * 4 + r;
    const float4 bi = sb[i];
    const float  ai = sa[i];
    const int b = i >> 6;
    const int base = tri_base(i);
    unsigned long long any = 0;
    for (int w = b; w < 16; ++w) {
      const int j = w * 64 + lane;
      const float4 bj = sb[j];
      const float lt0 = fmaxf(bi.x, bj.x), lt1 = fmaxf(bi.y, bj.y);
      const float rb0 = fminf(bi.z, bj.z), rb1 = fminf(bi.w, bj.w);
      const float wq = fmaxf(rb0 - lt0, 0.0f), hq = fmaxf(rb1 - lt1, 0.0f);
      const float inter = wq * hq;
      const float iou = inter / (ai + sa[j] - inter + 1e-8f);
      const unsigned long long bits = __ballot((j > i) && (iou > NMS_THR_F));
      any |= bits;
      if (lane == 0) Mtri[base + (w - b)] = bits;
    }
    if (lane == 0 && any)
      atomicOr(&rowAny[i >> 6], 1ull << (i & 63));
  }
}

// ---------------- NMS stage 3: barrier-free greedy scan (broadcast-read, rowAny-skip) ----------------
__global__ __launch_bounds__(1024) void scan_out_kernel(
    const unsigned long long* __restrict__ Mtri_g, const unsigned long long* __restrict__ rowAny_g,
    const int* __restrict__ order, const float4* __restrict__ sboxes,
    const float* __restrict__ obj_soft, const float* __restrict__ orient,
    float* __restrict__ out)
{
  __shared__ unsigned long long M[MTRI_WORDS];
  __shared__ unsigned long long rA[16];
  __shared__ unsigned long long keepw[16];
  const int tid = threadIdx.x;
  for (int t = tid; t < MTRI_WORDS; t += 1024) M[t] = Mtri_g[t];
  if (tid < 16) rA[tid] = rowAny_g[tid];
  __syncthreads();

  if (tid < 64) {
    const int lane = tid;
    unsigned long long kw = (lane < 16) ? ~0ull : 0ull;
    for (int w = 0; w < 16; ++w) {
      // only kept boxes that actually suppress someone need processing
      unsigned long long rem = __shfl(kw, w) & rA[w];
      while (rem) {
        const int bpos = __builtin_ctzll(rem);
        const int i = w * 64 + bpos;
        const int base = tri_base(i);   // i>>6 == w
        unsigned long long m = 0;
        if (lane >= w && lane < 16) m = M[base + (lane - w)];
        kw &= ~m;
        const unsigned long long m0 = M[base];   // uniform addr -> LDS broadcast
        rem = rem & ~m0 & ((bpos == 63) ? 0ull : (~0ull << (bpos + 1)));
      }
    }
    if (lane < 16) keepw[lane] = kw;
  }
  __syncthreads();

  const int w = tid >> 6, bpos = tid & 63;
  int pre = 0, total = 0;
#pragma unroll
  for (int q = 0; q < 16; ++q) {
    const int pc = __popcll(keepw[q]);
    total += pc;
    if (q < w) pre += pc;
  }
  pre += __popcll(keepw[w] & ((bpos == 0) ? 0ull : (~0ull >> (64 - bpos))));
  const int keep_self = (int)((keepw[w] >> bpos) & 1ull);
  const int rank = keep_self ? pre : (total + tid - pre);

  if (rank < NMS_OUT) {
    const int ob = order[tid];
    const float4 bx = sboxes[tid];
    out[rank*7+0] = obj_soft[ob*2+0];
    out[rank*7+1] = obj_soft[ob*2+1];
    out[rank*7+2] = bx.x;
    out[rank*7+3] = bx.y;
    out[rank*7+4] = bx.z;
    out[rank*7+5] = bx.w;
    out[rank*7+6] = orient[ob];
  }
}

extern "C" void kernel_launch(void* const* d_in, const int* in_sizes, int n_in,
                              void* d_out, int out_size, void* d_ws, size_t ws_size,
                              hipStream_t stream) {
  (void)in_sizes; (void)n_in; (void)out_size; (void)ws_size;
  const float* img       = (const float*)d_in[0];
  const float* bev       = (const float*)d_in[1];
  const float* img_boxes = (const float*)d_in[2];
  const float* bev_boxes = (const float*)d_in[3];
  const float* bev_abs   = (const float*)d_in[4];
  const float* img_mask  = (const float*)d_in[5];
  const float* bev_mask  = (const float*)d_in[6];
  const float* W1 = (const float*)d_in[7];
  const float* b1 = (const float*)d_in[8];
  const float* W2 = (const float*)d_in[9];
  const float* b2 = (const float*)d_in[10];
  const float* Wc = (const float*)d_in[11];
  const float* bc = (const float*)d_in[12];
  const float* Wo = (const float*)d_in[13];
  const float* bo = (const float*)d_in[14];
  const float* Wa = (const float*)d_in[15];
  const float* ba = (const float*)d_in[16];
  float* out = (float*)d_out;

  char* ws = (char*)d_ws;
  f16* xh    = (f16*)ws;                                  ws += (size_t)NBOX*K1PAD*2;
  f16* xl    = (f16*)ws;                                  ws += (size_t)NBOX*K1PAD*2;
  float* h1f = (float*)ws;                                ws += (size_t)NBOX*HD*4;
  f16* h1h   = (f16*)ws;                                  ws += (size_t)NBOX*HD*2;
  f16* h1l   = (f16*)ws;                                  ws += (size_t)NBOX*HD*2;
  float* h2f = (float*)ws;                                ws += (size_t)NBOX*HD*4;
  f16* Wt1h  = (f16*)ws;                                  ws += (size_t)HD*K1PAD*2;
  f16* Wt1l  = (f16*)ws;                                  ws += (size_t)HD*K1PAD*2;
  f16* Wt2h  = (f16*)ws;                                  ws += (size_t)HD*HD*2;
  f16* Wt2l  = (f16*)ws;                                  ws += (size_t)HD*HD*2;
  float* Wcat = (float*)ws;                               ws += 14*HD*4;
  float* obj_soft = (float*)ws;                           ws += NBOX*2*4;
  float* boxesf   = (float*)ws;                           ws += NBOX*4*4;
  float* orient   = (float*)ws;                           ws += NBOX*4;
  float* scores   = (float*)ws;                           ws += NBOX*4;
  int*   order    = (int*)ws;                             ws += NBOX*4;
  float4* sboxes  = (float4*)ws;                          ws += NBOX*16;
  float* sarea    = (float*)ws;                           ws += NBOX*4;
  unsigned long long* Mtri = (unsigned long long*)ws;     ws += MTRI_WORDS*8;
  unsigned long long* rowAny = (unsigned long long*)ws;   ws += 16*8;

  prep_kernel<<<B_ROI + B_C1 + B_C2 + B_INIT + B_HT, 256, 0, stream>>>(
      img, bev, img_boxes, bev_boxes, img_mask, bev_mask, xh, xl,
      W1, Wt1h, Wt1l, W2, Wt2h, Wt2l, b1, b2, (float4*)h1f, (float4*)h2f,
      Wc, Wo, Wa, Wcat, rowAny);
  gemm_sk<<<512, 256, 0, stream>>>(xh, xl, Wt1h, Wt1l, h1f, NBOX, HD, K1PAD, K1PAD/4);
  split_relu_kernel<<<NBOX*HD/4/256, 256, 0, stream>>>(h1f, h1h, h1l);
  gemm_sk<<<512, 256, 0, stream>>>(h1h, h1l, Wt2h, Wt2l, h2f, NBOX, HD, HD, HD/4);
  heads_kernel<<<NBOX, 256, 0, stream>>>(h2f, Wcat, bc, bo, ba, bev_abs,
                                         obj_soft, boxesf, orient, scores);
  sort_kernel<<<8, 128, 0, stream>>>(scores, boxesf, order, sboxes, sarea);
  maskbuild_kernel<<<64, 256, 0, stream>>>(sboxes, sarea, Mtri, rowAny);
  scan_out_kernel<<<1, 1024, 0, stream>>>(Mtri, rowAny, order, sboxes, obj_soft, orient, out);
}